// Round 5
// baseline (245.077 us; speedup 1.0000x reference)
//
#include <hip/hip_runtime.h>
#include <math.h>

// out[tok, d] = cos(dot(x[tok,:], W1) + b1) * cos(phi) * W2[d] + b2[d]
// D = 1024, tokens = B*S = 32768 (fixed by reference shape).
//
// Round 5: keep the 2-kernel split (q in workspace) but fix the latency duty
// cycle inside each phase:
//   phase 1: persistent waves, 4 contiguous tokens/wave, 2-deep register
//            double-buffer -> next token's 4 loads are ALWAYS in flight while
//            the current token's fma/shuffle/cos tail runs.
//   phase 2: fill-kernel structure. Thread t owns f4-slot t of a row; each
//            block writes 16 contiguous rows; q fetched once per block via 4
//            wave-uniform f4 loads; 16 independent fma+store pairs; plain
//            stores (fill kernel proves 6.7 TB/s with plain stores).

#define EMBED_D 1024
#define NTOK    (8 * 4096)
#define ROW_F4  (EMBED_D / 4)          // 256 f4 per row

#define P1_BLOCKS 2048
#define TPW1      4                    // tokens per wave (contiguous), phase 1
#define P2_BLOCKS 2048
#define TPB2      16                   // token rows per block, phase 2

typedef float f4 __attribute__((ext_vector_type(4)));

// ---------------- phase 1: q[tok] = cos(x.W1 + b1)*cos(phi) ----------------
__global__ __launch_bounds__(256) void ffq_theta(
    const float* __restrict__ x,
    const float* __restrict__ W1,
    const float* __restrict__ b1,
    const float* __restrict__ phi,
    float* __restrict__ q_ws)
{
    const int lane  = threadIdx.x & 63;
    const int wib   = threadIdx.x >> 6;
    const int tok0  = (blockIdx.x * 4 + wib) * TPW1;   // 4 contiguous tokens

    const f4* xb  = (const f4*)x + (size_t)tok0 * ROW_F4;
    const f4* w14 = (const f4*)W1;

    // broadcast operands once per wave
    f4 w1r[4];
    #pragma unroll
    for (int c = 0; c < 4; ++c) w1r[c] = w14[c * 64 + lane];
    const float b1v  = b1[0];
    const float cphi = cosf(phi[0]);

    // 2-deep pipeline: xd[t&1] is consumed while xd[(t+1)&1] is loading.
    // Fully unrolled -> all indices compile-time constants (no scratch).
    f4 xd[2][4];
    #pragma unroll
    for (int c = 0; c < 4; ++c) xd[0][c] = xb[c * 64 + lane];

    #pragma unroll
    for (int t = 0; t < TPW1; ++t) {
        const int cur = t & 1, nxt = cur ^ 1;
        if (t + 1 < TPW1) {
            #pragma unroll
            for (int c = 0; c < 4; ++c)
                xd[nxt][c] = xb[(t + 1) * ROW_F4 + c * 64 + lane];
        }

        float s = 0.f;
        #pragma unroll
        for (int c = 0; c < 4; ++c) {
            s = fmaf(xd[cur][c].x, w1r[c].x, s);
            s = fmaf(xd[cur][c].y, w1r[c].y, s);
            s = fmaf(xd[cur][c].z, w1r[c].z, s);
            s = fmaf(xd[cur][c].w, w1r[c].w, s);
        }
        #pragma unroll
        for (int m = 32; m > 0; m >>= 1)
            s += __shfl_xor(s, m, 64);

        if (lane == 0)
            q_ws[tok0 + t] = cosf(s + b1v) * cphi;   // 4B fire-and-forget
    }
}

// ---------------- phase 2: out[tok,:] = q[tok]*W2 + b2 ----------------
__global__ __launch_bounds__(256) void ffq_out(
    const float* __restrict__ q_ws,
    const float* __restrict__ W2,
    const float* __restrict__ b2,
    float* __restrict__ out)
{
    const int t = threadIdx.x;                        // f4 slot in row, 0..255

    const f4 w2v = ((const f4*)W2)[t];
    const f4 b2v = ((const f4*)b2)[t];

    // 16 q values for this block via 4 wave-uniform f4 loads (s_load-able)
    const f4* qb = (const f4*)q_ws + blockIdx.x * (TPB2 / 4);
    f4 q0 = qb[0], q1 = qb[1], q2 = qb[2], q3 = qb[3];
    const float qq[TPB2] = { q0.x,q0.y,q0.z,q0.w, q1.x,q1.y,q1.z,q1.w,
                             q2.x,q2.y,q2.z,q2.w, q3.x,q3.y,q3.z,q3.w };

    f4* ob = (f4*)out + (size_t)blockIdx.x * TPB2 * ROW_F4 + t;
    #pragma unroll
    for (int tt = 0; tt < TPB2; ++tt) {
        f4 o;
        o.x = fmaf(qq[tt], w2v.x, b2v.x);
        o.y = fmaf(qq[tt], w2v.y, b2v.y);
        o.z = fmaf(qq[tt], w2v.z, b2v.z);
        o.w = fmaf(qq[tt], w2v.w, b2v.w);
        ob[tt * ROW_F4] = o;                          // 16 independent 16B stores
    }
}

extern "C" void kernel_launch(void* const* d_in, const int* in_sizes, int n_in,
                              void* d_out, int out_size, void* d_ws, size_t ws_size,
                              hipStream_t stream) {
    const float* x   = (const float*)d_in[0];
    const float* W1  = (const float*)d_in[1];
    const float* b1  = (const float*)d_in[2];
    const float* phi = (const float*)d_in[3];
    const float* W2  = (const float*)d_in[4];
    const float* b2  = (const float*)d_in[5];
    float* out = (float*)d_out;
    float* q_ws = (float*)d_ws;        // 32768 floats = 128 KiB of workspace

    ffq_theta<<<P1_BLOCKS, 256, 0, stream>>>(x, W1, b1, phi, q_ws);
    ffq_out<<<P2_BLOCKS, 256, 0, stream>>>(q_ws, W2, b2, out);
}

// Round 6
// 243.666 us; speedup vs baseline: 1.0058x; 1.0058x over previous
//
#include <hip/hip_runtime.h>
#include <math.h>

// out[tok, d] = cos(dot(x[tok,:], W1) + b1) * cos(phi) * W2[d] + b2[d]
// D = 1024, tokens = B*S = 32768 (fixed by reference shape).
//
// Round 6: phase-1 pipeline, this time enforced.
// Evidence: r3's "issue 16 loads up front" compiled to VGPR=72 (needs ~130 to
// hold them) -> the scheduler SANK the loads back to their uses, serializing
// the wave: 4KB in flight, then a ~450cy reduce tail with zero memory
// outstanding (duty ~50% -> the observed ~2.4 TB/s read phase).
// Fix: load W1 (oldest), then ALL 32 x-loads (8 tokens) in consume order,
// then __builtin_amdgcn_sched_barrier(0) — nothing may cross. Consuming in
// issue order gives counted vmcnt drains (28,24,20,...), so tokens t+1..7
// stay in flight while token t's fma/shuffle/cos tail runs.
// Phase 2 (fill-structured rank-1 expand) unchanged from round 5.

#define EMBED_D 1024
#define NTOK    (8 * 4096)
#define ROW_F4  (EMBED_D / 4)          // 256 f4 per row
#define TPW1    8                      // tokens per wave, phase 1
#define TPB2    16                     // token rows per block, phase 2

typedef float f4 __attribute__((ext_vector_type(4)));

// ---------------- phase 1: q[tok] = cos(x.W1 + b1)*cos(phi) ----------------
// 32768/8 = 4096 waves = 1024 blocks x 4 waves. Expected VGPR ~160 (the 32
// in-flight f4 of x MUST be allocated now — that's the point).
__global__ __launch_bounds__(256) void ffq_theta(
    const float* __restrict__ x,
    const float* __restrict__ W1,
    const float* __restrict__ b1,
    const float* __restrict__ phi,
    float* __restrict__ q_ws)
{
    const int lane = threadIdx.x & 63;
    const int wib  = threadIdx.x >> 6;
    const int tok0 = (blockIdx.x * 4 + wib) * TPW1;

    const f4* xb  = (const f4*)x + (size_t)tok0 * ROW_F4;
    const f4* w14 = (const f4*)W1;

    // W1 first: oldest in the vmcnt queue, so consuming it only requires
    // vmcnt(32) — all x-loads may remain outstanding.
    f4 w1r[4];
    #pragma unroll
    for (int c = 0; c < 4; ++c) w1r[c] = w14[c * 64 + lane];

    // All 32 x-loads, token-major (consume order).
    f4 xv[TPW1][4];
    #pragma unroll
    for (int t = 0; t < TPW1; ++t)
        #pragma unroll
        for (int c = 0; c < 4; ++c)
            xv[t][c] = xb[t * ROW_F4 + c * 64 + lane];

    // Hard fence: the scheduler may not sink any load below this point nor
    // hoist any consume above it.
    __builtin_amdgcn_sched_barrier(0);

    const float b1v  = b1[0];
    const float cphi = cosf(phi[0]);

    #pragma unroll
    for (int t = 0; t < TPW1; ++t) {
        float s = 0.f;
        #pragma unroll
        for (int c = 0; c < 4; ++c) {
            s = fmaf(xv[t][c].x, w1r[c].x, s);
            s = fmaf(xv[t][c].y, w1r[c].y, s);
            s = fmaf(xv[t][c].z, w1r[c].z, s);
            s = fmaf(xv[t][c].w, w1r[c].w, s);
        }
        #pragma unroll
        for (int m = 32; m > 0; m >>= 1)
            s += __shfl_xor(s, m, 64);
        if (lane == 0)
            q_ws[tok0 + t] = cosf(s + b1v) * cphi;   // 4B fire-and-forget
    }
}

// ---------------- phase 2: out[tok,:] = q[tok]*W2 + b2 ----------------
// Fill-kernel structure: thread t owns f4-slot t of a row; block writes 16
// contiguous rows; q fetched once via 4 wave-uniform f4 loads; plain stores.
__global__ __launch_bounds__(256) void ffq_out(
    const float* __restrict__ q_ws,
    const float* __restrict__ W2,
    const float* __restrict__ b2,
    float* __restrict__ out)
{
    const int t = threadIdx.x;                        // f4 slot in row, 0..255

    const f4 w2v = ((const f4*)W2)[t];
    const f4 b2v = ((const f4*)b2)[t];

    const f4* qb = (const f4*)q_ws + blockIdx.x * (TPB2 / 4);
    f4 q0 = qb[0], q1 = qb[1], q2 = qb[2], q3 = qb[3];
    const float qq[TPB2] = { q0.x,q0.y,q0.z,q0.w, q1.x,q1.y,q1.z,q1.w,
                             q2.x,q2.y,q2.z,q2.w, q3.x,q3.y,q3.z,q3.w };

    f4* ob = (f4*)out + (size_t)blockIdx.x * TPB2 * ROW_F4 + t;
    #pragma unroll
    for (int tt = 0; tt < TPB2; ++tt) {
        f4 o;
        o.x = fmaf(qq[tt], w2v.x, b2v.x);
        o.y = fmaf(qq[tt], w2v.y, b2v.y);
        o.z = fmaf(qq[tt], w2v.z, b2v.z);
        o.w = fmaf(qq[tt], w2v.w, b2v.w);
        ob[tt * ROW_F4] = o;                          // 16 independent 16B stores
    }
}

extern "C" void kernel_launch(void* const* d_in, const int* in_sizes, int n_in,
                              void* d_out, int out_size, void* d_ws, size_t ws_size,
                              hipStream_t stream) {
    const float* x   = (const float*)d_in[0];
    const float* W1  = (const float*)d_in[1];
    const float* b1  = (const float*)d_in[2];
    const float* phi = (const float*)d_in[3];
    const float* W2  = (const float*)d_in[4];
    const float* b2  = (const float*)d_in[5];
    float* out = (float*)d_out;
    float* q_ws = (float*)d_ws;        // 32768 floats = 128 KiB of workspace

    ffq_theta<<<NTOK / (4 * TPW1), 256, 0, stream>>>(x, W1, b1, phi, q_ws);
    ffq_out<<<NTOK / TPB2, 256, 0, stream>>>(q_ws, W2, b2, out);
}